// Round 1
// baseline (3722.456 us; speedup 1.0000x reference)
//
#include <hip/hip_runtime.h>

#define S_LEN 2048
#define H_DIM 1536
#define NQ_H 12
#define NKV_H 2
#define HD 128
#define I_DIM 8960
#define QKV_N 2048
#define GU_N 17920
#define SCALE 0.08838834764831845f

typedef _Float16 f16;
typedef _Float16 f16x8 __attribute__((ext_vector_type(8)));
typedef float f32x4 __attribute__((ext_vector_type(4)));

__device__ __forceinline__ void gload16(const void* g, void* l) {
  __builtin_amdgcn_global_load_lds((__attribute__((address_space(1))) void*)g,
                                   (__attribute__((address_space(3))) void*)l,
                                   16, 0, 0);
}

// ---------------- GEMM: C[M,N] = A[M,K] (f16) @ BT[N,K]^T (f16) ----------------
// MODE 0: Cf = acc (f32)   MODE 1: Cf += acc (f32, in-place residual)   MODE 2: Ch = acc (f16)
template <int MODE>
__global__ __launch_bounds__(256) void gemm_bt(const f16* __restrict__ A,
                                               const f16* __restrict__ BT,
                                               float* __restrict__ Cf,
                                               f16* __restrict__ Ch,
                                               int M, int N, int K) {
  __shared__ __attribute__((aligned(16))) f16 As[128 * 32];
  __shared__ __attribute__((aligned(16))) f16 Bs[128 * 32];
  const int tid = threadIdx.x;
  const int w = tid >> 6, lane = tid & 63;
  const int quad = lane >> 4, cc = lane & 15;
  const int wm = w >> 1, wn = w & 1;
  const int m0 = blockIdx.y * 128, n0 = blockIdx.x * 128;

  const int c1 = tid, c2 = tid + 256;
  const f16* Ag1 = A + (size_t)(m0 + (c1 >> 2)) * K + (c1 & 3) * 8;
  const f16* Ag2 = A + (size_t)(m0 + (c2 >> 2)) * K + (c2 & 3) * 8;
  const f16* Bg1 = BT + (size_t)(n0 + (c1 >> 2)) * K + (c1 & 3) * 8;
  const f16* Bg2 = BT + (size_t)(n0 + (c2 >> 2)) * K + (c2 & 3) * 8;
  f16* Al1 = As + (w * 64) * 8;
  f16* Al2 = As + (256 + w * 64) * 8;
  f16* Bl1 = Bs + (w * 64) * 8;
  f16* Bl2 = Bs + (256 + w * 64) * 8;

  const f32x4 fz = {0.f, 0.f, 0.f, 0.f};
  f32x4 acc[4][4];
#pragma unroll
  for (int i = 0; i < 4; ++i)
#pragma unroll
    for (int j = 0; j < 4; ++j) acc[i][j] = fz;

  for (int k0 = 0; k0 < K; k0 += 32) {
    __syncthreads();
    gload16(Ag1 + k0, Al1);
    gload16(Ag2 + k0, Al2);
    gload16(Bg1 + k0, Bl1);
    gload16(Bg2 + k0, Bl2);
    __syncthreads();
    f16x8 af[4], bf[4];
#pragma unroll
    for (int i = 0; i < 4; ++i)
      af[i] = *(const f16x8*)(As + (wm * 64 + i * 16 + cc) * 32 + quad * 8);
#pragma unroll
    for (int j = 0; j < 4; ++j)
      bf[j] = *(const f16x8*)(Bs + (wn * 64 + j * 16 + cc) * 32 + quad * 8);
#pragma unroll
    for (int i = 0; i < 4; ++i)
#pragma unroll
      for (int j = 0; j < 4; ++j)
        acc[i][j] = __builtin_amdgcn_mfma_f32_16x16x32_f16(af[i], bf[j], acc[i][j], 0, 0, 0);
  }

#pragma unroll
  for (int i = 0; i < 4; ++i) {
    const int row = m0 + wm * 64 + i * 16 + quad * 4;
#pragma unroll
    for (int j = 0; j < 4; ++j) {
      const int col = n0 + wn * 64 + j * 16 + cc;
#pragma unroll
      for (int r = 0; r < 4; ++r) {
        const size_t idx = (size_t)(row + r) * N + col;
        if (MODE == 0) Cf[idx] = acc[i][j][r];
        else if (MODE == 1) Cf[idx] += acc[i][j][r];
        else Ch[idx] = (f16)acc[i][j][r];
      }
    }
  }
}

// ---------------- transpose + f32->f16: src[K_][N_] f32 -> dst[N_][K_] f16 ----------------
__global__ __launch_bounds__(256) void transpose_f2h(const float* __restrict__ src,
                                                     f16* __restrict__ dst,
                                                     int K_, int N_) {
  __shared__ float tile[32][33];
  const int c0 = blockIdx.x * 32, r0 = blockIdx.y * 32;
  const int x = threadIdx.x & 31, y4 = threadIdx.x >> 5;
#pragma unroll
  for (int i = 0; i < 4; ++i) {
    int r = r0 + y4 + i * 8;
    if (r < K_ && c0 + x < N_) tile[y4 + i * 8][x] = src[(size_t)r * N_ + c0 + x];
  }
  __syncthreads();
#pragma unroll
  for (int i = 0; i < 4; ++i) {
    int rr = y4 + i * 8;
    int dr = c0 + rr, dc = r0 + x;
    if (dr < N_ && dc < K_) dst[(size_t)dr * K_ + dc] = (f16)tile[x][rr];
  }
}

// ---------------- RMSNorm ----------------
template <bool OUT_F32>
__global__ __launch_bounds__(256) void rmsnorm_kernel(const float* __restrict__ x,
                                                      const float* __restrict__ w,
                                                      f16* __restrict__ hh,
                                                      float* __restrict__ hf) {
  const int s = blockIdx.x;
  const float* xr = x + (size_t)s * H_DIM;
  float ss = 0.f;
  for (int i = threadIdx.x; i < H_DIM; i += 256) {
    float v = xr[i];
    ss += v * v;
  }
#pragma unroll
  for (int m = 32; m >= 1; m >>= 1) ss += __shfl_xor(ss, m);
  __shared__ float red[4];
  if ((threadIdx.x & 63) == 0) red[threadIdx.x >> 6] = ss;
  __syncthreads();
  ss = red[0] + red[1] + red[2] + red[3];
  const float rr = rsqrtf(ss * (1.0f / H_DIM) + 1e-6f);
  for (int i = threadIdx.x; i < H_DIM; i += 256) {
    float v = xr[i] * rr * w[i];
    if (OUT_F32) hf[(size_t)s * H_DIM + i] = v;
    else hh[(size_t)s * H_DIM + i] = (f16)v;
  }
}

// ---------------- RoPE + bias + layout split ----------------
// qkv[s][0..2047] f32 -> q_r [NQ][S][D] f16 (roped), k_r [NKV][S][D] f16 (roped),
// v_r [NKV][D][S] f16 (transposed)
__global__ __launch_bounds__(256) void rope_kernel(const float* __restrict__ qkv,
                                                   const float* __restrict__ cosb,
                                                   const float* __restrict__ sinb,
                                                   const float* __restrict__ bq,
                                                   const float* __restrict__ bk,
                                                   const float* __restrict__ bv,
                                                   f16* __restrict__ q_r,
                                                   f16* __restrict__ k_r,
                                                   f16* __restrict__ v_r) {
  const int s = blockIdx.x;
  const float* row = qkv + (size_t)s * QKV_N;
#pragma unroll
  for (int ci = 0; ci < 8; ++ci) {
    const int col = ci * 256 + threadIdx.x;
    if (col < 1536) {
      const int hh = col >> 7, d = col & 127;
      const int part = (d < 64) ? d + 64 : d - 64;
      const float v0 = row[col] + bq[col];
      const float v1 = row[(hh << 7) + part] + bq[(hh << 7) + part];
      const float cs = cosb[s * HD + d], sn = sinb[s * HD + d];
      const float rot = (d < 64) ? -v1 : v1;
      q_r[((size_t)hh * S_LEN + s) * HD + d] = (f16)(v0 * cs + rot * sn);
    } else if (col < 1792) {
      const int cc2 = col - 1536;
      const int hh = cc2 >> 7, d = cc2 & 127;
      const int part = (d < 64) ? d + 64 : d - 64;
      const float v0 = row[col] + bk[cc2];
      const float v1 = row[1536 + (hh << 7) + part] + bk[(hh << 7) + part];
      const float cs = cosb[s * HD + d], sn = sinb[s * HD + d];
      const float rot = (d < 64) ? -v1 : v1;
      k_r[((size_t)hh * S_LEN + s) * HD + d] = (f16)(v0 * cs + rot * sn);
    } else {
      const int cc2 = col - 1792;
      const int hh = cc2 >> 7, d = cc2 & 127;
      const float v0 = row[col] + bv[cc2];
      v_r[((size_t)hh * HD + d) * S_LEN + s] = (f16)v0;
    }
  }
}

// ---------------- fused flash attention ----------------
// grid (NQ, S/128); block 256 (4 waves, each owns 32 q-rows)
__global__ __launch_bounds__(256) void attn_kernel(const f16* __restrict__ Q,
                                                   const f16* __restrict__ Kc,
                                                   const f16* __restrict__ Vt,
                                                   f16* __restrict__ Oa) {
  __shared__ __attribute__((aligned(16))) f16 ks[64 * 136];   // [kv 64][d 128 +8]
  __shared__ __attribute__((aligned(16))) f16 vs[128 * 72];   // [d 128][kv 64 +8]
  __shared__ __attribute__((aligned(16))) f16 ps[128 * 72];   // [q 128][kv 64 +8]
  const int h = blockIdx.x, qt = blockIdx.y;
  const int hk = h / (NQ_H / NKV_H);
  const int tid = threadIdx.x, w = tid >> 6, lane = tid & 63;
  const int quad = lane >> 4, cc = lane & 15;

  // Q fragments in registers: rows qt*128 + w*32 + i*16 + cc, k = kk*32 + quad*8
  f16x8 qf[2][4];
  const f16* Qg = Q + ((size_t)h * S_LEN + qt * 128) * HD;
#pragma unroll
  for (int i = 0; i < 2; ++i)
#pragma unroll
    for (int kk = 0; kk < 4; ++kk)
      qf[i][kk] = *(const f16x8*)(Qg + (size_t)(w * 32 + i * 16 + cc) * HD + kk * 32 + quad * 8);

  const f32x4 fz = {0.f, 0.f, 0.f, 0.f};
  f32x4 o_acc[2][8];
  float m_run[2][4], l_run[2][4];
#pragma unroll
  for (int i = 0; i < 2; ++i) {
#pragma unroll
    for (int j = 0; j < 8; ++j) o_acc[i][j] = fz;
#pragma unroll
    for (int r = 0; r < 4; ++r) { m_run[i][r] = -1e30f; l_run[i][r] = 0.f; }
  }

  const int nkt = 2 * qt + 2;
  for (int kt = 0; kt < nkt; ++kt) {
    const int kv0 = kt * 64;
    __syncthreads();
    // stage K tile (64 kv rows x 128 d)
    const f16* Kg = Kc + ((size_t)hk * S_LEN + kv0) * HD;
    for (int t = tid; t < 64 * 16; t += 256) {
      int r = t >> 4, ch = t & 15;
      *(uint4*)(ks + r * 136 + ch * 8) = *(const uint4*)(Kg + (size_t)r * HD + ch * 8);
    }
    // stage V^T tile (128 d rows x 64 kv)
    const f16* Vg = Vt + (size_t)hk * HD * S_LEN + kv0;
    for (int t = tid; t < 128 * 8; t += 256) {
      int r = t >> 3, ch = t & 7;
      *(uint4*)(vs + r * 72 + ch * 8) = *(const uint4*)(Vg + (size_t)r * S_LEN + ch * 8);
    }
    __syncthreads();

    // S = Q K^T : sc[2][4]
    f32x4 sc[2][4];
#pragma unroll
    for (int i = 0; i < 2; ++i)
#pragma unroll
      for (int j = 0; j < 4; ++j) sc[i][j] = fz;
#pragma unroll
    for (int kk = 0; kk < 4; ++kk) {
      f16x8 bfr[4];
#pragma unroll
      for (int j = 0; j < 4; ++j)
        bfr[j] = *(const f16x8*)(ks + (j * 16 + cc) * 136 + kk * 32 + quad * 8);
#pragma unroll
      for (int i = 0; i < 2; ++i)
#pragma unroll
        for (int j = 0; j < 4; ++j)
          sc[i][j] = __builtin_amdgcn_mfma_f32_16x16x32_f16(qf[i][kk], bfr[j], sc[i][j], 0, 0, 0);
    }

    // scale + causal mask
    const bool need_mask = (kv0 + 63) > (qt * 128);
#pragma unroll
    for (int i = 0; i < 2; ++i)
#pragma unroll
      for (int j = 0; j < 4; ++j)
#pragma unroll
        for (int r = 0; r < 4; ++r) {
          float v = sc[i][j][r] * SCALE;
          if (need_mask) {
            int rowg = qt * 128 + w * 32 + i * 16 + quad * 4 + r;
            int colg = kv0 + j * 16 + cc;
            if (colg > rowg) v = -1e30f;
          }
          sc[i][j][r] = v;
        }

    // online softmax per row; write P (f16) to LDS
#pragma unroll
    for (int i = 0; i < 2; ++i)
#pragma unroll
      for (int r = 0; r < 4; ++r) {
        float mx = sc[i][0][r];
#pragma unroll
        for (int j = 1; j < 4; ++j) mx = fmaxf(mx, sc[i][j][r]);
        mx = fmaxf(mx, __shfl_xor(mx, 1));
        mx = fmaxf(mx, __shfl_xor(mx, 2));
        mx = fmaxf(mx, __shfl_xor(mx, 4));
        mx = fmaxf(mx, __shfl_xor(mx, 8));
        const float mnew = fmaxf(m_run[i][r], mx);
        const float alpha = __expf(m_run[i][r] - mnew);
        m_run[i][r] = mnew;
        l_run[i][r] *= alpha;
#pragma unroll
        for (int jd = 0; jd < 8; ++jd) o_acc[i][jd][r] *= alpha;
        float rs = 0.f;
        const int prow = w * 32 + i * 16 + quad * 4 + r;
#pragma unroll
        for (int j = 0; j < 4; ++j) {
          float p = __expf(sc[i][j][r] - mnew);
          rs += p;
          ps[prow * 72 + j * 16 + cc] = (f16)p;
        }
        rs += __shfl_xor(rs, 1);
        rs += __shfl_xor(rs, 2);
        rs += __shfl_xor(rs, 4);
        rs += __shfl_xor(rs, 8);
        l_run[i][r] += rs;
      }

    // O += P V   (P: A-operand from LDS; V^T: B-operand)
#pragma unroll
    for (int kk = 0; kk < 2; ++kk) {
      f16x8 pa[2];
#pragma unroll
      for (int i = 0; i < 2; ++i)
        pa[i] = *(const f16x8*)(ps + (w * 32 + i * 16 + cc) * 72 + kk * 32 + quad * 8);
#pragma unroll
      for (int j = 0; j < 8; ++j) {
        f16x8 vb = *(const f16x8*)(vs + (j * 16 + cc) * 72 + kk * 32 + quad * 8);
#pragma unroll
        for (int i = 0; i < 2; ++i)
          o_acc[i][j] = __builtin_amdgcn_mfma_f32_16x16x32_f16(pa[i], vb, o_acc[i][j], 0, 0, 0);
      }
    }
  }

  // epilogue: O /= l, write [S][NQ*D]
#pragma unroll
  for (int i = 0; i < 2; ++i)
#pragma unroll
    for (int j = 0; j < 8; ++j)
#pragma unroll
      for (int r = 0; r < 4; ++r) {
        const int rowg = qt * 128 + w * 32 + i * 16 + quad * 4 + r;
        const int colg = j * 16 + cc;
        Oa[(size_t)rowg * H_DIM + h * HD + colg] = (f16)(o_acc[i][j][r] / l_run[i][r]);
      }
}

// ---------------- SiLU(gate) * up ----------------
__global__ __launch_bounds__(256) void silu_mul(const f16* __restrict__ gu,
                                                f16* __restrict__ hm) {
  const int i = blockIdx.x * 256 + threadIdx.x;
  const int s = blockIdx.y;
  const float g = (float)gu[(size_t)s * GU_N + i];
  const float u = (float)gu[(size_t)s * GU_N + I_DIM + i];
  const float sig = 1.f / (1.f + __expf(-g));
  hm[(size_t)s * I_DIM + i] = (f16)(g * sig * u);
}

extern "C" void kernel_launch(void* const* d_in, const int* in_sizes, int n_in,
                              void* d_out, int out_size, void* d_ws, size_t ws_size,
                              hipStream_t stream) {
  const float* hidden = (const float*)d_in[0];
  const float* cosb   = (const float*)d_in[1];
  const float* sinb   = (const float*)d_in[2];
  const float* Wq     = (const float*)d_in[4];
  const float* bq     = (const float*)d_in[5];
  const float* Wk     = (const float*)d_in[6];
  const float* bk     = (const float*)d_in[7];
  const float* Wv     = (const float*)d_in[8];
  const float* bv     = (const float*)d_in[9];
  const float* Wo     = (const float*)d_in[10];
  const float* Wg     = (const float*)d_in[11];
  const float* Wu     = (const float*)d_in[12];
  const float* Wd     = (const float*)d_in[13];
  const float* ln1    = (const float*)d_in[14];
  const float* ln2    = (const float*)d_in[15];
  const float* lnf    = (const float*)d_in[16];

  char* wp = (char*)d_ws;
  auto take = [&](size_t bytes) {
    void* p = (void*)wp;
    wp += (bytes + 255) & ~(size_t)255;
    return p;
  };
  f16* wqkvT  = (f16*)take((size_t)QKV_N * H_DIM * 2);
  f16* woT    = (f16*)take((size_t)H_DIM * H_DIM * 2);
  f16* wguT   = (f16*)take((size_t)GU_N * H_DIM * 2);
  f16* wdT    = (f16*)take((size_t)H_DIM * I_DIM * 2);
  float* x    = (float*)take((size_t)S_LEN * H_DIM * 4);
  f16* hbuf   = (f16*)take((size_t)S_LEN * H_DIM * 2);
  float* qkv  = (float*)take((size_t)S_LEN * QKV_N * 4);
  f16* q_r    = (f16*)take((size_t)NQ_H * S_LEN * HD * 2);
  f16* k_r    = (f16*)take((size_t)NKV_H * S_LEN * HD * 2);
  f16* v_r    = (f16*)take((size_t)NKV_H * HD * S_LEN * 2);
  f16* gu     = (f16*)take((size_t)S_LEN * GU_N * 2);
  f16* hmid   = (f16*)take((size_t)S_LEN * I_DIM * 2);

  hipMemcpyAsync(x, hidden, (size_t)S_LEN * H_DIM * 4, hipMemcpyDeviceToDevice, stream);

  for (int l = 0; l < 4; ++l) {
    // per-layer weight transposes (fp32 -> fp16, B^T layout)
    transpose_f2h<<<dim3(48, 48), 256, 0, stream>>>(Wq + (size_t)l * H_DIM * 1536, wqkvT, H_DIM, 1536);
    transpose_f2h<<<dim3(8, 48), 256, 0, stream>>>(Wk + (size_t)l * H_DIM * 256, wqkvT + (size_t)1536 * H_DIM, H_DIM, 256);
    transpose_f2h<<<dim3(8, 48), 256, 0, stream>>>(Wv + (size_t)l * H_DIM * 256, wqkvT + (size_t)1792 * H_DIM, H_DIM, 256);
    transpose_f2h<<<dim3(48, 48), 256, 0, stream>>>(Wo + (size_t)l * H_DIM * H_DIM, woT, H_DIM, H_DIM);
    transpose_f2h<<<dim3(280, 48), 256, 0, stream>>>(Wg + (size_t)l * H_DIM * I_DIM, wguT, H_DIM, I_DIM);
    transpose_f2h<<<dim3(280, 48), 256, 0, stream>>>(Wu + (size_t)l * H_DIM * I_DIM, wguT + (size_t)I_DIM * H_DIM, H_DIM, I_DIM);
    transpose_f2h<<<dim3(48, 280), 256, 0, stream>>>(Wd + (size_t)l * I_DIM * H_DIM, wdT, I_DIM, H_DIM);

    rmsnorm_kernel<false><<<S_LEN, 256, 0, stream>>>(x, ln1 + l * H_DIM, hbuf, nullptr);
    gemm_bt<0><<<dim3(QKV_N / 128, S_LEN / 128), 256, 0, stream>>>(hbuf, wqkvT, qkv, nullptr, S_LEN, QKV_N, H_DIM);
    rope_kernel<<<S_LEN, 256, 0, stream>>>(qkv, cosb, sinb, bq + l * 1536, bk + l * 256, bv + l * 256, q_r, k_r, v_r);
    attn_kernel<<<dim3(NQ_H, S_LEN / 128), 256, 0, stream>>>(q_r, k_r, v_r, hbuf);
    gemm_bt<1><<<dim3(H_DIM / 128, S_LEN / 128), 256, 0, stream>>>(hbuf, woT, x, nullptr, S_LEN, H_DIM, H_DIM);
    rmsnorm_kernel<false><<<S_LEN, 256, 0, stream>>>(x, ln2 + l * H_DIM, hbuf, nullptr);
    gemm_bt<2><<<dim3(GU_N / 128, S_LEN / 128), 256, 0, stream>>>(hbuf, wguT, nullptr, gu, S_LEN, GU_N, H_DIM);
    silu_mul<<<dim3(I_DIM / 256, S_LEN), 256, 0, stream>>>(gu, hmid);
    gemm_bt<1><<<dim3(H_DIM / 128, S_LEN / 128), 256, 0, stream>>>(hmid, wdT, x, nullptr, S_LEN, H_DIM, I_DIM);
  }
  rmsnorm_kernel<true><<<S_LEN, 256, 0, stream>>>(x, lnf, nullptr, (float*)d_out);
}

// Round 2
// 3093.969 us; speedup vs baseline: 1.2031x; 1.2031x over previous
//
#include <hip/hip_runtime.h>

#define S_LEN 2048
#define H_DIM 1536
#define NQ_H 12
#define NKV_H 2
#define HD 128
#define I_DIM 8960
#define QKV_N 2048
#define GU_N 17920
#define SCALE 0.08838834764831845f

typedef _Float16 f16;
typedef _Float16 f16x8 __attribute__((ext_vector_type(8)));
typedef float f32x4 __attribute__((ext_vector_type(4)));

__device__ __forceinline__ void gload16(const void* g, void* l) {
  __builtin_amdgcn_global_load_lds((__attribute__((address_space(1))) void*)g,
                                   (__attribute__((address_space(3))) void*)l,
                                   16, 0, 0);
}

// ---------------- GEMM: C[M,N](+)= A[M,K] (f16) @ BT[N,K]^T (f16) ----------------
// Split-K via blockIdx.z: each z handles K-range [z*Kc, (z+1)*Kc) of row stride Ktot.
// MODE 1: unsafeAtomicAdd into Cf (f32; caller pre-fills with residual or zeros)
// MODE 2: Ch = acc (f16 store; requires gridDim.z == 1)
template <int MODE>
__global__ __launch_bounds__(256) void gemm_bt(const f16* __restrict__ A,
                                               const f16* __restrict__ BT,
                                               float* __restrict__ Cf,
                                               f16* __restrict__ Ch,
                                               int N, int Ktot, int Kc) {
  __shared__ __attribute__((aligned(16))) f16 As[128 * 32];
  __shared__ __attribute__((aligned(16))) f16 Bs[128 * 32];
  const int tid = threadIdx.x;
  const int w = tid >> 6, lane = tid & 63;
  const int quad = lane >> 4, cc = lane & 15;
  const int wm = w >> 1, wn = w & 1;
  const int m0 = blockIdx.y * 128, n0 = blockIdx.x * 128;
  const int kbase = blockIdx.z * Kc;

  const int c1 = tid, c2 = tid + 256;
  const f16* Ag1 = A + (size_t)(m0 + (c1 >> 2)) * Ktot + kbase + (c1 & 3) * 8;
  const f16* Ag2 = A + (size_t)(m0 + (c2 >> 2)) * Ktot + kbase + (c2 & 3) * 8;
  const f16* Bg1 = BT + (size_t)(n0 + (c1 >> 2)) * Ktot + kbase + (c1 & 3) * 8;
  const f16* Bg2 = BT + (size_t)(n0 + (c2 >> 2)) * Ktot + kbase + (c2 & 3) * 8;
  f16* Al1 = As + (w * 64) * 8;
  f16* Al2 = As + (256 + w * 64) * 8;
  f16* Bl1 = Bs + (w * 64) * 8;
  f16* Bl2 = Bs + (256 + w * 64) * 8;

  const f32x4 fz = {0.f, 0.f, 0.f, 0.f};
  f32x4 acc[4][4];
#pragma unroll
  for (int i = 0; i < 4; ++i)
#pragma unroll
    for (int j = 0; j < 4; ++j) acc[i][j] = fz;

  for (int k0 = 0; k0 < Kc; k0 += 32) {
    __syncthreads();
    gload16(Ag1 + k0, Al1);
    gload16(Ag2 + k0, Al2);
    gload16(Bg1 + k0, Bl1);
    gload16(Bg2 + k0, Bl2);
    __syncthreads();
    f16x8 af[4], bf[4];
#pragma unroll
    for (int i = 0; i < 4; ++i)
      af[i] = *(const f16x8*)(As + (wm * 64 + i * 16 + cc) * 32 + quad * 8);
#pragma unroll
    for (int j = 0; j < 4; ++j)
      bf[j] = *(const f16x8*)(Bs + (wn * 64 + j * 16 + cc) * 32 + quad * 8);
#pragma unroll
    for (int i = 0; i < 4; ++i)
#pragma unroll
      for (int j = 0; j < 4; ++j)
        acc[i][j] = __builtin_amdgcn_mfma_f32_16x16x32_f16(af[i], bf[j], acc[i][j], 0, 0, 0);
  }

#pragma unroll
  for (int i = 0; i < 4; ++i) {
    const int row = m0 + wm * 64 + i * 16 + quad * 4;
#pragma unroll
    for (int j = 0; j < 4; ++j) {
      const int col = n0 + wn * 64 + j * 16 + cc;
#pragma unroll
      for (int r = 0; r < 4; ++r) {
        const size_t idx = (size_t)(row + r) * N + col;
        if (MODE == 1) unsafeAtomicAdd(&Cf[idx], acc[i][j][r]);
        else Ch[idx] = (f16)acc[i][j][r];
      }
    }
  }
}

// ---------------- transpose + f32->f16: src[K_][N_] f32 -> dst[N_][K_] f16 ----------------
__global__ __launch_bounds__(256) void transpose_f2h(const float* __restrict__ src,
                                                     f16* __restrict__ dst,
                                                     int K_, int N_) {
  __shared__ float tile[32][33];
  const int c0 = blockIdx.x * 32, r0 = blockIdx.y * 32;
  const int x = threadIdx.x & 31, y4 = threadIdx.x >> 5;
#pragma unroll
  for (int i = 0; i < 4; ++i) {
    int r = r0 + y4 + i * 8;
    if (r < K_ && c0 + x < N_) tile[y4 + i * 8][x] = src[(size_t)r * N_ + c0 + x];
  }
  __syncthreads();
#pragma unroll
  for (int i = 0; i < 4; ++i) {
    int rr = y4 + i * 8;
    int dr = c0 + rr, dc = r0 + x;
    if (dr < N_ && dc < K_) dst[(size_t)dr * K_ + dc] = (f16)tile[x][rr];
  }
}

// ---------------- RMSNorm ----------------
template <bool OUT_F32>
__global__ __launch_bounds__(256) void rmsnorm_kernel(const float* __restrict__ x,
                                                      const float* __restrict__ w,
                                                      f16* __restrict__ hh,
                                                      float* __restrict__ hf) {
  const int s = blockIdx.x;
  const float* xr = x + (size_t)s * H_DIM;
  float ss = 0.f;
  for (int i = threadIdx.x; i < H_DIM; i += 256) {
    float v = xr[i];
    ss += v * v;
  }
#pragma unroll
  for (int m = 32; m >= 1; m >>= 1) ss += __shfl_xor(ss, m);
  __shared__ float red[4];
  if ((threadIdx.x & 63) == 0) red[threadIdx.x >> 6] = ss;
  __syncthreads();
  ss = red[0] + red[1] + red[2] + red[3];
  const float rr = rsqrtf(ss * (1.0f / H_DIM) + 1e-6f);
  for (int i = threadIdx.x; i < H_DIM; i += 256) {
    float v = xr[i] * rr * w[i];
    if (OUT_F32) hf[(size_t)s * H_DIM + i] = v;
    else hh[(size_t)s * H_DIM + i] = (f16)v;
  }
}

// ---------------- RoPE + bias + layout split ----------------
__global__ __launch_bounds__(256) void rope_kernel(const float* __restrict__ qkv,
                                                   const float* __restrict__ cosb,
                                                   const float* __restrict__ sinb,
                                                   const float* __restrict__ bq,
                                                   const float* __restrict__ bk,
                                                   const float* __restrict__ bv,
                                                   f16* __restrict__ q_r,
                                                   f16* __restrict__ k_r,
                                                   f16* __restrict__ v_r) {
  const int s = blockIdx.x;
  const float* row = qkv + (size_t)s * QKV_N;
#pragma unroll
  for (int ci = 0; ci < 8; ++ci) {
    const int col = ci * 256 + threadIdx.x;
    if (col < 1536) {
      const int hh = col >> 7, d = col & 127;
      const int part = (d < 64) ? d + 64 : d - 64;
      const float v0 = row[col] + bq[col];
      const float v1 = row[(hh << 7) + part] + bq[(hh << 7) + part];
      const float cs = cosb[s * HD + d], sn = sinb[s * HD + d];
      const float rot = (d < 64) ? -v1 : v1;
      q_r[((size_t)hh * S_LEN + s) * HD + d] = (f16)(v0 * cs + rot * sn);
    } else if (col < 1792) {
      const int cc2 = col - 1536;
      const int hh = cc2 >> 7, d = cc2 & 127;
      const int part = (d < 64) ? d + 64 : d - 64;
      const float v0 = row[col] + bk[cc2];
      const float v1 = row[1536 + (hh << 7) + part] + bk[(hh << 7) + part];
      const float cs = cosb[s * HD + d], sn = sinb[s * HD + d];
      const float rot = (d < 64) ? -v1 : v1;
      k_r[((size_t)hh * S_LEN + s) * HD + d] = (f16)(v0 * cs + rot * sn);
    } else {
      const int cc2 = col - 1792;
      const int hh = cc2 >> 7, d = cc2 & 127;
      const float v0 = row[col] + bv[cc2];
      v_r[((size_t)hh * HD + d) * S_LEN + s] = (f16)v0;
    }
  }
}

// ---------------- fused flash attention (64-row Q tiles) ----------------
// grid (NQ, S/64); block 256 (4 waves, each owns 16 q-rows)
__global__ __launch_bounds__(256) void attn_kernel(const f16* __restrict__ Q,
                                                   const f16* __restrict__ Kc,
                                                   const f16* __restrict__ Vt,
                                                   f16* __restrict__ Oa) {
  __shared__ __attribute__((aligned(16))) f16 ks[64 * 136];   // [kv 64][d 128 +8]
  __shared__ __attribute__((aligned(16))) f16 vs[128 * 72];   // [d 128][kv 64 +8]
  __shared__ __attribute__((aligned(16))) f16 ps[64 * 72];    // [q 64][kv 64 +8]
  const int h = blockIdx.x, qt = blockIdx.y;
  const int hk = h / (NQ_H / NKV_H);
  const int tid = threadIdx.x, w = tid >> 6, lane = tid & 63;
  const int quad = lane >> 4, cc = lane & 15;

  // Q fragments: wave w owns q-rows qt*64 + w*16 + [0,16); A-frag row m = cc
  f16x8 qf[4];
  const f16* Qg = Q + ((size_t)h * S_LEN + qt * 64) * HD;
#pragma unroll
  for (int kk = 0; kk < 4; ++kk)
    qf[kk] = *(const f16x8*)(Qg + (size_t)(w * 16 + cc) * HD + kk * 32 + quad * 8);

  const f32x4 fz = {0.f, 0.f, 0.f, 0.f};
  f32x4 o_acc[8];
  float m_run[4], l_run[4];
#pragma unroll
  for (int j = 0; j < 8; ++j) o_acc[j] = fz;
#pragma unroll
  for (int r = 0; r < 4; ++r) { m_run[r] = -1e30f; l_run[r] = 0.f; }

  const int nkt = qt + 1;
  for (int kt = 0; kt < nkt; ++kt) {
    const int kv0 = kt * 64;
    __syncthreads();
    // stage K tile (64 kv rows x 128 d)
    const f16* Kg = Kc + ((size_t)hk * S_LEN + kv0) * HD;
    for (int t = tid; t < 64 * 16; t += 256) {
      int r = t >> 4, ch = t & 15;
      *(uint4*)(ks + r * 136 + ch * 8) = *(const uint4*)(Kg + (size_t)r * HD + ch * 8);
    }
    // stage V^T tile (128 d rows x 64 kv)
    const f16* Vg = Vt + (size_t)hk * HD * S_LEN + kv0;
    for (int t = tid; t < 128 * 8; t += 256) {
      int r = t >> 3, ch = t & 7;
      *(uint4*)(vs + r * 72 + ch * 8) = *(const uint4*)(Vg + (size_t)r * S_LEN + ch * 8);
    }
    __syncthreads();

    // S = Q K^T
    f32x4 sc[4];
#pragma unroll
    for (int j = 0; j < 4; ++j) sc[j] = fz;
#pragma unroll
    for (int kk = 0; kk < 4; ++kk) {
      f16x8 bfr[4];
#pragma unroll
      for (int j = 0; j < 4; ++j)
        bfr[j] = *(const f16x8*)(ks + (j * 16 + cc) * 136 + kk * 32 + quad * 8);
#pragma unroll
      for (int j = 0; j < 4; ++j)
        sc[j] = __builtin_amdgcn_mfma_f32_16x16x32_f16(qf[kk], bfr[j], sc[j], 0, 0, 0);
    }

    // scale + causal mask (only the diagonal tile needs the mask)
    const bool need_mask = (kt == qt);
#pragma unroll
    for (int j = 0; j < 4; ++j)
#pragma unroll
      for (int r = 0; r < 4; ++r) {
        float v = sc[j][r] * SCALE;
        if (need_mask) {
          int rowg = qt * 64 + w * 16 + quad * 4 + r;
          int colg = kv0 + j * 16 + cc;
          if (colg > rowg) v = -1e30f;
        }
        sc[j][r] = v;
      }

    // online softmax per row; P (f16) to LDS
#pragma unroll
    for (int r = 0; r < 4; ++r) {
      float mx = sc[0][r];
#pragma unroll
      for (int j = 1; j < 4; ++j) mx = fmaxf(mx, sc[j][r]);
      mx = fmaxf(mx, __shfl_xor(mx, 1));
      mx = fmaxf(mx, __shfl_xor(mx, 2));
      mx = fmaxf(mx, __shfl_xor(mx, 4));
      mx = fmaxf(mx, __shfl_xor(mx, 8));
      const float mnew = fmaxf(m_run[r], mx);
      const float alpha = __expf(m_run[r] - mnew);
      m_run[r] = mnew;
      l_run[r] *= alpha;
#pragma unroll
      for (int jd = 0; jd < 8; ++jd) o_acc[jd][r] *= alpha;
      float rs = 0.f;
      const int prow = w * 16 + quad * 4 + r;
#pragma unroll
      for (int j = 0; j < 4; ++j) {
        float p = __expf(sc[j][r] - mnew);
        rs += p;
        ps[prow * 72 + j * 16 + cc] = (f16)p;
      }
      rs += __shfl_xor(rs, 1);
      rs += __shfl_xor(rs, 2);
      rs += __shfl_xor(rs, 4);
      rs += __shfl_xor(rs, 8);
      l_run[r] += rs;
    }

    // O += P V
#pragma unroll
    for (int kk = 0; kk < 2; ++kk) {
      f16x8 pa = *(const f16x8*)(ps + (w * 16 + cc) * 72 + kk * 32 + quad * 8);
#pragma unroll
      for (int j = 0; j < 8; ++j) {
        f16x8 vb = *(const f16x8*)(vs + (j * 16 + cc) * 72 + kk * 32 + quad * 8);
        o_acc[j] = __builtin_amdgcn_mfma_f32_16x16x32_f16(pa, vb, o_acc[j], 0, 0, 0);
      }
    }
  }

  // epilogue
#pragma unroll
  for (int j = 0; j < 8; ++j)
#pragma unroll
    for (int r = 0; r < 4; ++r) {
      const int rowg = qt * 64 + w * 16 + quad * 4 + r;
      const int colg = j * 16 + cc;
      Oa[(size_t)rowg * H_DIM + h * HD + colg] = (f16)(o_acc[j][r] / l_run[r]);
    }
}

// ---------------- SiLU(gate) * up ----------------
__global__ __launch_bounds__(256) void silu_mul(const f16* __restrict__ gu,
                                                f16* __restrict__ hm) {
  const int i = blockIdx.x * 256 + threadIdx.x;
  const int s = blockIdx.y;
  const float g = (float)gu[(size_t)s * GU_N + i];
  const float u = (float)gu[(size_t)s * GU_N + I_DIM + i];
  const float sig = 1.f / (1.f + __expf(-g));
  hm[(size_t)s * I_DIM + i] = (f16)(g * sig * u);
}

extern "C" void kernel_launch(void* const* d_in, const int* in_sizes, int n_in,
                              void* d_out, int out_size, void* d_ws, size_t ws_size,
                              hipStream_t stream) {
  const float* hidden = (const float*)d_in[0];
  const float* cosb   = (const float*)d_in[1];
  const float* sinb   = (const float*)d_in[2];
  const float* Wq     = (const float*)d_in[4];
  const float* bq     = (const float*)d_in[5];
  const float* Wk     = (const float*)d_in[6];
  const float* bk     = (const float*)d_in[7];
  const float* Wv     = (const float*)d_in[8];
  const float* bv     = (const float*)d_in[9];
  const float* Wo     = (const float*)d_in[10];
  const float* Wg     = (const float*)d_in[11];
  const float* Wu     = (const float*)d_in[12];
  const float* Wd     = (const float*)d_in[13];
  const float* ln1    = (const float*)d_in[14];
  const float* ln2    = (const float*)d_in[15];
  const float* lnf    = (const float*)d_in[16];

  char* wp = (char*)d_ws;
  auto take = [&](size_t bytes) {
    void* p = (void*)wp;
    wp += (bytes + 255) & ~(size_t)255;
    return p;
  };
  f16* wqkvT  = (f16*)take((size_t)QKV_N * H_DIM * 2);
  f16* woT    = (f16*)take((size_t)H_DIM * H_DIM * 2);
  f16* wguT   = (f16*)take((size_t)GU_N * H_DIM * 2);
  f16* wdT    = (f16*)take((size_t)H_DIM * I_DIM * 2);
  float* x    = (float*)take((size_t)S_LEN * H_DIM * 4);
  f16* hbuf   = (f16*)take((size_t)S_LEN * H_DIM * 2);
  float* qkv  = (float*)take((size_t)S_LEN * QKV_N * 4);
  f16* q_r    = (f16*)take((size_t)NQ_H * S_LEN * HD * 2);
  f16* k_r    = (f16*)take((size_t)NKV_H * S_LEN * HD * 2);
  f16* v_r    = (f16*)take((size_t)NKV_H * HD * S_LEN * 2);
  f16* gu     = (f16*)take((size_t)S_LEN * GU_N * 2);
  f16* hmid   = (f16*)take((size_t)S_LEN * I_DIM * 2);

  hipMemcpyAsync(x, hidden, (size_t)S_LEN * H_DIM * 4, hipMemcpyDeviceToDevice, stream);

  for (int l = 0; l < 4; ++l) {
    transpose_f2h<<<dim3(48, 48), 256, 0, stream>>>(Wq + (size_t)l * H_DIM * 1536, wqkvT, H_DIM, 1536);
    transpose_f2h<<<dim3(8, 48), 256, 0, stream>>>(Wk + (size_t)l * H_DIM * 256, wqkvT + (size_t)1536 * H_DIM, H_DIM, 256);
    transpose_f2h<<<dim3(8, 48), 256, 0, stream>>>(Wv + (size_t)l * H_DIM * 256, wqkvT + (size_t)1792 * H_DIM, H_DIM, 256);
    transpose_f2h<<<dim3(48, 48), 256, 0, stream>>>(Wo + (size_t)l * H_DIM * H_DIM, woT, H_DIM, H_DIM);
    transpose_f2h<<<dim3(280, 48), 256, 0, stream>>>(Wg + (size_t)l * H_DIM * I_DIM, wguT, H_DIM, I_DIM);
    transpose_f2h<<<dim3(280, 48), 256, 0, stream>>>(Wu + (size_t)l * H_DIM * I_DIM, wguT + (size_t)I_DIM * H_DIM, H_DIM, I_DIM);
    transpose_f2h<<<dim3(48, 280), 256, 0, stream>>>(Wd + (size_t)l * I_DIM * H_DIM, wdT, I_DIM, H_DIM);

    rmsnorm_kernel<false><<<S_LEN, 256, 0, stream>>>(x, ln1 + l * H_DIM, hbuf, nullptr);
    hipMemsetAsync(qkv, 0, (size_t)S_LEN * QKV_N * 4, stream);
    gemm_bt<1><<<dim3(QKV_N / 128, S_LEN / 128, 2), 256, 0, stream>>>(hbuf, wqkvT, qkv, nullptr, QKV_N, H_DIM, 768);
    rope_kernel<<<S_LEN, 256, 0, stream>>>(qkv, cosb, sinb, bq + l * 1536, bk + l * 256, bv + l * 256, q_r, k_r, v_r);
    attn_kernel<<<dim3(NQ_H, S_LEN / 64), 256, 0, stream>>>(q_r, k_r, v_r, hbuf);
    gemm_bt<1><<<dim3(H_DIM / 128, S_LEN / 128, 4), 256, 0, stream>>>(hbuf, woT, x, nullptr, H_DIM, H_DIM, 384);
    rmsnorm_kernel<false><<<S_LEN, 256, 0, stream>>>(x, ln2 + l * H_DIM, hbuf, nullptr);
    gemm_bt<2><<<dim3(GU_N / 128, S_LEN / 128, 1), 256, 0, stream>>>(hbuf, wguT, nullptr, gu, GU_N, H_DIM, H_DIM);
    silu_mul<<<dim3(I_DIM / 256, S_LEN), 256, 0, stream>>>(gu, hmid);
    gemm_bt<1><<<dim3(H_DIM / 128, S_LEN / 128, 4), 256, 0, stream>>>(hmid, wdT, x, nullptr, H_DIM, I_DIM, 2240);
  }
  rmsnorm_kernel<true><<<S_LEN, 256, 0, stream>>>(x, lnf, nullptr, (float*)d_out);
}